// Round 11
// baseline (1851.246 us; speedup 1.0000x reference)
//
#include <hip/hip_runtime.h>
#include <hip/hip_fp16.h>
#include <math.h>

#define DIM 128
#define E_NUM 100000
#define P_NUM 800000
#define G_NUM 1000
#define T_STEPS 8
#define R_UNITS 256

typedef __attribute__((ext_vector_type(8))) short bf16x8;   // 8 bf16 = 4 VGPRs
typedef __attribute__((ext_vector_type(4))) float f32x4;    // 16x16 MFMA acc

typedef unsigned short ushort_t;
typedef unsigned int   uint_t;

__device__ __forceinline__ float selu_f(float x) {
    const float alpha = 1.6732632423543772f;
    const float scale = 1.0507009873554805f;
    return x > 0.f ? scale * x : scale * alpha * expm1f(x);
}

// Fast selu for the hot aggregation path: A*exp2(x*log2e)-A instead of
// libm expm1f (~15-20 VALU ops -> 1 mul + 1 v_exp_f32 + 1 fma).
__device__ __forceinline__ float selu_fast(float x) {
    const float scale = 1.0507009873554805f;
    const float A     = 1.7580993408473766f;    // scale*alpha
    const float l2e   = 1.4426950408889634f;
    const float e = __builtin_amdgcn_exp2f(x * l2e);
    return x > 0.f ? scale * x : A * e - A;
}

__device__ __forceinline__ ushort_t f2bf(float x) {
    uint_t u = __float_as_uint(x);
    uint_t r = (u + 0x7fffu + ((u >> 16) & 1u)) >> 16;
    return (ushort_t)r;
}
__device__ __forceinline__ float bf2f(ushort_t h) {
    return __uint_as_float(((uint_t)h) << 16);
}

// ===========================================================================
// CSR build (once per launch). Multi-block scan.
// ===========================================================================
__global__ __launch_bounds__(256)
void hist_kernel(const int* __restrict__ second, int* __restrict__ counts)
{
    const int p = blockIdx.x * 256 + threadIdx.x;
    atomicAdd(&counts[second[p]], 1);
}

__global__ __launch_bounds__(1024)
void scanA_kernel(const int* __restrict__ counts, int* __restrict__ offsets,
                  int* __restrict__ bsum)
{
    __shared__ int buf[1024];
    const int i = blockIdx.x * 1024 + threadIdx.x;
    const int v = (i < E_NUM) ? counts[i] : 0;
    buf[threadIdx.x] = v;
    __syncthreads();
    for (int off = 1; off < 1024; off <<= 1) {
        const int t = (threadIdx.x >= off) ? buf[threadIdx.x - off] : 0;
        __syncthreads();
        buf[threadIdx.x] += t;
        __syncthreads();
    }
    if (i < E_NUM) offsets[i] = buf[threadIdx.x] - v;   // block-local exclusive
    if (threadIdx.x == 1023) bsum[blockIdx.x] = buf[1023];
}

__global__ void scanB_kernel(int* __restrict__ bsum, int* __restrict__ offsets)
{
    int acc = 0;
    for (int b = 0; b < 98; b++) { const int t = bsum[b]; bsum[b] = acc; acc += t; }
    offsets[E_NUM] = P_NUM;
}

__global__ __launch_bounds__(1024)
void scanC_kernel(int* __restrict__ offsets, const int* __restrict__ bsum)
{
    const int i = blockIdx.x * 1024 + threadIdx.x;
    if (i < E_NUM) offsets[i] += bsum[blockIdx.x];
}

__global__ __launch_bounds__(256)
void fill_kernel(const int* __restrict__ first, const int* __restrict__ second,
                 const int* __restrict__ offsets, int* __restrict__ cursor,
                 int* __restrict__ sfirst, int* __restrict__ ssecond)
{
    const int p = blockIdx.x * 256 + threadIdx.x;
    const int d = second[p];
    const int pos = atomicAdd(&cursor[d], 1);
    const int idx = offsets[d] + pos;
    sfirst[idx] = first[p];
    ssecond[idx] = d;
}

// ===========================================================================
// One-time prep (unchanged).
// ===========================================================================
__global__ __launch_bounds__(256)
void cast_h_kernel(const float* __restrict__ src,
                   ushort_t* __restrict__ dhi, ushort_t* __restrict__ dlo)
{
    const int idx = blockIdx.x * 256 + threadIdx.x;
    const float x = src[idx];
    const ushort_t hi = f2bf(x);
    dhi[idx] = hi;
    dlo[idx] = f2bf(x - bf2f(hi));
}

__global__ __launch_bounds__(256)
void wsplit_build_kernel(const float* __restrict__ Wmsg,
                         ushort_t* __restrict__ wt, ushort_t* __restrict__ wy)
{
    const int idx  = blockIdx.x * 256 + threadIdx.x;   // 8192 slots (2 halves)
    const int lane = idx & 63;
    const int nt   = (idx >> 6) & 7;
    const int comp = (idx >> 9) & 1;
    const int ks   = (idx >> 10) & 3;
    const int half = idx >> 12;
    const int n    = nt * 16 + (lane & 15);
    const int kb   = ks * 32 + (lane >> 4) * 8 + half * 128;
    ushort_t* dst  = half ? wy : wt;
    const int slot = idx & 4095;
#pragma unroll
    for (int j = 0; j < 8; j++) {
        const float w = Wmsg[(size_t)(kb + j) * DIM + n];
        const ushort_t hi = f2bf(w);
        dst[(size_t)slot * 8 + j] = comp ? f2bf(w - bf2f(hi)) : hi;
    }
}

__global__ __launch_bounds__(256)
void wb_build_kernel(const float* __restrict__ K, const float* __restrict__ U,
                     ushort_t* __restrict__ wb)
{
    const int idx  = blockIdx.x * 256 + threadIdx.x;   // 24576 slots
    const int lane = idx & 63;
    int t = idx >> 6;
    const int nt   = t % 24;  t /= 24;
    const int comp = t & 1;   t >>= 1;
    const int gemm = t & 1;
    const int ks   = t >> 1;
    const float* src = gemm ? U : K;
    const int n  = nt * 16 + (lane & 15);
    const int kb = ks * 32 + (lane >> 4) * 8;
#pragma unroll
    for (int j = 0; j < 8; j++) {
        const float w = src[(size_t)(kb + j) * 384 + n];
        const ushort_t hi = f2bf(w);
        wb[(size_t)idx * 8 + j] = comp ? f2bf(w - bf2f(hi)) : hi;
    }
}

// ===========================================================================
// GY kernel (R17 structure, R23 fp16-G output kept).
// ===========================================================================
#define AS1(p) ((const __attribute__((address_space(1))) unsigned int*)(p))
#define AS3(p) ((__attribute__((address_space(3))) unsigned int*)(p))

__global__ __launch_bounds__(256, 4)
void gy_kernel(const ushort_t* __restrict__ hbh, const ushort_t* __restrict__ hbl,
               const ushort_t* __restrict__ wt, const ushort_t* __restrict__ wy,
               const float* __restrict__ bmsg,
               __half* __restrict__ Gh, float* __restrict__ Y2b)
{
    __shared__ __align__(16) ushort_t sact[2][4096];   // hh, hl (8KB each)

    const int tid  = threadIdx.x;
    const int lane = tid & 63;
    const int w    = tid >> 6;
    const int e0   = blockIdx.x * 32;
    const int m16  = lane & 15;
    const int quad = lane >> 4;

    // stage acts in fragment order: granule g = gk*128 + gq*32 + gr*16 + gm
#pragma unroll
    for (int i = 0; i < 2; i++) {
        const int g  = tid + i * 256;
        const int gm = g & 15;
        const int gr = (g >> 4) & 1;
        const int gq = (g >> 5) & 3;
        const int gk = g >> 7;
        const size_t soff = (size_t)(e0 + gr * 16 + gm) * DIM + gk * 32 + gq * 8;
        __builtin_amdgcn_global_load_lds(AS1(hbh + soff), AS3((char*)sact[0] + g * 16), 16, 0, 0);
        __builtin_amdgcn_global_load_lds(AS1(hbl + soff), AS3((char*)sact[1] + g * 16), 16, 0, 0);
    }
    __syncthreads();   // single prologue drain

#define ACT(a_, ks_, rt_) \
    (*(const bf16x8*)((const char*)sact[a_] + (size_t)((ks_) * 2048 + quad * 512 + (rt_) * 256 + m16 * 16)))

    f32x4 acc[2][4] = {};
#pragma unroll
    for (int ks = 0; ks < 4; ks++) {
        bf16x8 ah[2], al[2];
#pragma unroll
        for (int rt = 0; rt < 2; rt++) {
            ah[rt] = ACT(0, ks, rt);
            al[rt] = ACT(1, ks, rt);
        }
#pragma unroll
        for (int ntl = 0; ntl < 4; ntl++) {
            const int ntg = w * 4 + ntl;                    // 0..15
            const ushort_t* wsel = (ntg < 8) ? wt : wy;
            const int nt = ntg & 7;
            const bf16x8 bh = *(const bf16x8*)(wsel + (size_t)(((ks * 2 + 0) * 8 + nt) * 64 + lane) * 8);
            const bf16x8 bl = *(const bf16x8*)(wsel + (size_t)(((ks * 2 + 1) * 8 + nt) * 64 + lane) * 8);
#pragma unroll
            for (int rt = 0; rt < 2; rt++) {
                acc[rt][ntl] = __builtin_amdgcn_mfma_f32_16x16x32_bf16(ah[rt], bh, acc[rt][ntl], 0, 0, 0);
                acc[rt][ntl] = __builtin_amdgcn_mfma_f32_16x16x32_bf16(al[rt], bh, acc[rt][ntl], 0, 0, 0);
                acc[rt][ntl] = __builtin_amdgcn_mfma_f32_16x16x32_bf16(ah[rt], bl, acc[rt][ntl], 0, 0, 0);
            }
        }
    }
#undef ACT
    // C layout: col = lane&15, row = quad*4 + reg
#pragma unroll
    for (int ntl = 0; ntl < 4; ntl++) {
        const int ntg = w * 4 + ntl;
        const int c   = (ntg & 7) * 16 + m16;               // 0..127 within half
        if (ntg < 8) {
            // G half: store fp16 (gather-path compression)
#pragma unroll
            for (int rt = 0; rt < 2; rt++) {
#pragma unroll
                for (int reg = 0; reg < 4; reg++) {
                    const size_t row = (size_t)(e0 + rt * 16 + quad * 4 + reg);
                    Gh[row * DIM + c] = __float2half_rn(acc[rt][ntl][reg]);
                }
            }
        } else {
            const float bb = bmsg[c];
#pragma unroll
            for (int rt = 0; rt < 2; rt++) {
#pragma unroll
                for (int reg = 0; reg < 4; reg++) {
                    const size_t row = (size_t)(e0 + rt * 16 + quad * 4 + reg);
                    Y2b[row * DIM + c] = acc[rt][ntl][reg] + bb;
                }
            }
        }
    }
}

// ===========================================================================
// agg_csr kernel (R23 structure kept): fp16 G gather, named scalars +
// __forceinline__ helper, 8-deep G-load batches.
// ===========================================================================
__device__ __forceinline__ void agg_one_dest(
    const __half2* __restrict__ Gh2, const int* __restrict__ sfirst,
    ushort_t* __restrict__ agg_hi, ushort_t* __restrict__ agg_lo,
    int d, int start, int end, float2 y, int c2, int lane)
{
    float a0 = 0.f, a1 = 0.f;
    int p = start;
    for (; p + 8 <= end; p += 8) {
        int f[8];
#pragma unroll
        for (int j = 0; j < 8; j++) f[j] = sfirst[p + j];
        __half2 g[8];
#pragma unroll
        for (int j = 0; j < 8; j++)
            g[j] = Gh2[(size_t)f[j] * 64 + lane];
#pragma unroll
        for (int j = 0; j < 8; j++) {
            const float2 gf = __half22float2(g[j]);
            a0 += selu_fast(gf.x + y.x);
            a1 += selu_fast(gf.y + y.y);
        }
    }
    if (p + 4 <= end) {
        int f[4];
#pragma unroll
        for (int j = 0; j < 4; j++) f[j] = sfirst[p + j];
        __half2 g[4];
#pragma unroll
        for (int j = 0; j < 4; j++)
            g[j] = Gh2[(size_t)f[j] * 64 + lane];
#pragma unroll
        for (int j = 0; j < 4; j++) {
            const float2 gf = __half22float2(g[j]);
            a0 += selu_fast(gf.x + y.x);
            a1 += selu_fast(gf.y + y.y);
        }
        p += 4;
    }
    for (; p < end; p++) {
        const int f = sfirst[p];
        const float2 gf = __half22float2(Gh2[(size_t)f * 64 + lane]);
        a0 += selu_fast(gf.x + y.x);
        a1 += selu_fast(gf.y + y.y);
    }
    const ushort_t h0 = f2bf(a0);
    const ushort_t h1 = f2bf(a1);
    ushort2 hv, lv;
    hv.x = h0;  hv.y = h1;
    lv.x = f2bf(a0 - bf2f(h0));
    lv.y = f2bf(a1 - bf2f(h1));
    *(ushort2*)(agg_hi + (size_t)d * DIM + c2) = hv;
    *(ushort2*)(agg_lo + (size_t)d * DIM + c2) = lv;
}

__global__ __launch_bounds__(256)
void agg_csr_kernel(const __half2* __restrict__ Gh2, const float* __restrict__ Y2b,
                    const int* __restrict__ offsets, const int* __restrict__ sfirst,
                    ushort_t* __restrict__ agg_hi, ushort_t* __restrict__ agg_lo)
{
    const int tid  = threadIdx.x;
    const int lane = tid & 63;
    const int wv   = blockIdx.x * 4 + (tid >> 6);   // global wave id, 0..12499
    const int c2   = lane * 2;
    const int d0   = wv * 8;

    // hoist: 9 boundary offsets + 8 y-vectors, all NAMED scalars (no arrays)
    const int o0 = offsets[d0 + 0], o1 = offsets[d0 + 1], o2 = offsets[d0 + 2];
    const int o3 = offsets[d0 + 3], o4 = offsets[d0 + 4], o5 = offsets[d0 + 5];
    const int o6 = offsets[d0 + 6], o7 = offsets[d0 + 7], o8 = offsets[d0 + 8];
    const float2* Yp = (const float2*)(Y2b + (size_t)d0 * DIM + c2);
    const float2 y0 = Yp[0],  y1 = Yp[64],  y2 = Yp[128], y3 = Yp[192];
    const float2 y4 = Yp[256], y5 = Yp[320], y6 = Yp[384], y7 = Yp[448];

    agg_one_dest(Gh2, sfirst, agg_hi, agg_lo, d0 + 0, o0, o1, y0, c2, lane);
    agg_one_dest(Gh2, sfirst, agg_hi, agg_lo, d0 + 1, o1, o2, y1, c2, lane);
    agg_one_dest(Gh2, sfirst, agg_hi, agg_lo, d0 + 2, o2, o3, y2, c2, lane);
    agg_one_dest(Gh2, sfirst, agg_hi, agg_lo, d0 + 3, o3, o4, y3, c2, lane);
    agg_one_dest(Gh2, sfirst, agg_hi, agg_lo, d0 + 4, o4, o5, y4, c2, lane);
    agg_one_dest(Gh2, sfirst, agg_hi, agg_lo, d0 + 5, o5, o6, y5, c2, lane);
    agg_one_dest(Gh2, sfirst, agg_hi, agg_lo, d0 + 6, o6, o7, y6, c2, lane);
    agg_one_dest(Gh2, sfirst, agg_hi, agg_lo, d0 + 7, o7, o8, y7, c2, lane);
}

// ===========================================================================
// GRU kernel, R24: rt=4 (64 rows/block) with LDS-staged acts.
//
// R23 arithmetic: weight L2 stream 35us + MFMA 28us + VALU 26us ~= 84us
// measured -> components barely overlap; weights are the largest term and
// only rows-per-block reduces them. Prior failures were specific: R15
// (rt=4, acts from GLOBAL -> serialized VMEM chains), R19 (64 rows via 16
// waves -> barrier over 64 DMAs). Untried quadrant: rt=4 + 512 thr/8 waves
// + LDS acts. Weights 1.2GB -> 600MB/step, 48 loads/wave reused 4x.
// Per-row MFMA sequence identical to R20 -> bit-identical output.
// Tail block: DMA rows clamped, stores guarded.
// ===========================================================================
__global__ __launch_bounds__(512, 2)
void gru_kernel(const ushort_t* __restrict__ xhg, const ushort_t* __restrict__ xlg,
                ushort_t* __restrict__ hbh, ushort_t* __restrict__ hbl,
                const ushort_t* __restrict__ wb, const float* __restrict__ bias)
{
    __shared__ __align__(16) ushort_t sact[4][8192];   // xh, xl, hh, hl (16KB each)

    const int tid  = threadIdx.x;
    const int lane = tid & 63;
    const int w    = tid >> 6;          // 0..7
    const int e0   = blockIdx.x * 64;
    const int m16  = lane & 15;
    const int quad = lane >> 4;

    // ---- stage acts in fragment order: granule g = gk*256 + gq*64 + grt*16 + gm
#pragma unroll
    for (int i = 0; i < 2; i++) {
        const int g   = tid + i * 512;
        const int gm  = g & 15;
        const int grt = (g >> 4) & 3;
        const int gq  = (g >> 6) & 3;
        const int gk  = g >> 8;
        int srow = e0 + grt * 16 + gm;
        if (srow >= E_NUM) srow = E_NUM - 1;            // tail clamp (loads only)
        const size_t soff = (size_t)srow * DIM + gk * 32 + gq * 8;
        __builtin_amdgcn_global_load_lds(AS1(xhg + soff), AS3((char*)sact[0] + g * 16), 16, 0, 0);
        __builtin_amdgcn_global_load_lds(AS1(xlg + soff), AS3((char*)sact[1] + g * 16), 16, 0, 0);
        __builtin_amdgcn_global_load_lds(AS1(hbh + soff), AS3((char*)sact[2] + g * 16), 16, 0, 0);
        __builtin_amdgcn_global_load_lds(AS1(hbl + soff), AS3((char*)sact[3] + g * 16), 16, 0, 0);
    }
    __syncthreads();   // single prologue drain; no barriers after this

    f32x4 az[4] = {}, ar[4] = {}, ahx[4] = {}, ahh[4] = {};

#define WB(ks_, gm_, cp_, nt_) \
    (*(const bf16x8*)(wb + ((size_t)(((ks_) * 96) + (gm_) * 48 + (cp_) * 24 + (nt_)) * 64 + lane) * 8))
#define ACT(a_, ks_, rt_) \
    (*(const bf16x8*)((const char*)sact[a_] + (size_t)((ks_) * 4096 + quad * 1024 + (rt_) * 256 + m16 * 16)))

#pragma unroll
    for (int ks = 0; ks < 4; ks++) {
        const bf16x8 KzH = WB(ks, 0, 0, w),      KzL = WB(ks, 0, 1, w);
        const bf16x8 UzH = WB(ks, 1, 0, w),      UzL = WB(ks, 1, 1, w);
        const bf16x8 KrH = WB(ks, 0, 0, w + 8),  KrL = WB(ks, 0, 1, w + 8);
        const bf16x8 UrH = WB(ks, 1, 0, w + 8),  UrL = WB(ks, 1, 1, w + 8);
        const bf16x8 KhH = WB(ks, 0, 0, w + 16), KhL = WB(ks, 0, 1, w + 16);
        const bf16x8 UhH = WB(ks, 1, 0, w + 16), UhL = WB(ks, 1, 1, w + 16);
#pragma unroll
        for (int rt = 0; rt < 4; rt++) {
            const bf16x8 xh = ACT(0, ks, rt);
            const bf16x8 xl = ACT(1, ks, rt);
            const bf16x8 hh = ACT(2, ks, rt);
            const bf16x8 hl = ACT(3, ks, rt);

            az[rt] = __builtin_amdgcn_mfma_f32_16x16x32_bf16(xh, KzH, az[rt], 0, 0, 0);
            az[rt] = __builtin_amdgcn_mfma_f32_16x16x32_bf16(xl, KzH, az[rt], 0, 0, 0);
            az[rt] = __builtin_amdgcn_mfma_f32_16x16x32_bf16(xh, KzL, az[rt], 0, 0, 0);
            az[rt] = __builtin_amdgcn_mfma_f32_16x16x32_bf16(hh, UzH, az[rt], 0, 0, 0);
            az[rt] = __builtin_amdgcn_mfma_f32_16x16x32_bf16(hl, UzH, az[rt], 0, 0, 0);
            az[rt] = __builtin_amdgcn_mfma_f32_16x16x32_bf16(hh, UzL, az[rt], 0, 0, 0);

            ar[rt] = __builtin_amdgcn_mfma_f32_16x16x32_bf16(xh, KrH, ar[rt], 0, 0, 0);
            ar[rt] = __builtin_amdgcn_mfma_f32_16x16x32_bf16(xl, KrH, ar[rt], 0, 0, 0);
            ar[rt] = __builtin_amdgcn_mfma_f32_16x16x32_bf16(xh, KrL, ar[rt], 0, 0, 0);
            ar[rt] = __builtin_amdgcn_mfma_f32_16x16x32_bf16(hh, UrH, ar[rt], 0, 0, 0);
            ar[rt] = __builtin_amdgcn_mfma_f32_16x16x32_bf16(hl, UrH, ar[rt], 0, 0, 0);
            ar[rt] = __builtin_amdgcn_mfma_f32_16x16x32_bf16(hh, UrL, ar[rt], 0, 0, 0);

            ahx[rt] = __builtin_amdgcn_mfma_f32_16x16x32_bf16(xh, KhH, ahx[rt], 0, 0, 0);
            ahx[rt] = __builtin_amdgcn_mfma_f32_16x16x32_bf16(xl, KhH, ahx[rt], 0, 0, 0);
            ahx[rt] = __builtin_amdgcn_mfma_f32_16x16x32_bf16(xh, KhL, ahx[rt], 0, 0, 0);
            ahh[rt] = __builtin_amdgcn_mfma_f32_16x16x32_bf16(hh, UhH, ahh[rt], 0, 0, 0);
            ahh[rt] = __builtin_amdgcn_mfma_f32_16x16x32_bf16(hl, UhH, ahh[rt], 0, 0, 0);
            ahh[rt] = __builtin_amdgcn_mfma_f32_16x16x32_bf16(hh, UhL, ahh[rt], 0, 0, 0);
        }
    }
#undef WB
#undef ACT

    const int c = w * 16 + m16;
    const float l2e  = 1.4426950408889634f;
    const float bzn  = -(bias[c] + bias[384 + c]) * l2e;          // pre-scaled
    const float brn  = -(bias[128 + c] + bias[512 + c]) * l2e;
    const float bxh  = bias[256 + c];
    const float brh  = bias[640 + c];
    const float bxh2 = bxh * (2.f * l2e);

    // h_prev from the staged LDS copy (pre-update bits, exact):
    const int ksc   = w >> 1;
    const int quadc = (2 * w + (m16 >> 3)) & 3;
    const int elem  = m16 & 7;

#pragma unroll
    for (int rt = 0; rt < 4; rt++) {
#pragma unroll
        for (int reg = 0; reg < 4; reg++) {
            const int row  = e0 + rt * 16 + quad * 4 + reg;
            if (row < E_NUM) {
                const int lidx = (ksc * 256 + quadc * 64 + rt * 16 + (quad * 4 + reg)) * 8 + elem;
                // sigmoid via exp2+rcp (bias pre-folded with -log2e)
                const float z = __builtin_amdgcn_rcpf(
                    1.f + __builtin_amdgcn_exp2f(fmaf(az[rt][reg], -l2e, bzn)));
                const float r = __builtin_amdgcn_rcpf(
                    1.f + __builtin_amdgcn_exp2f(fmaf(ar[rt][reg], -l2e, brn)));
                // tanh(s) = 1 - 2/(exp2(2*l2e*s)+1); s = ahx+bxh + r*(ahh+brh)
                const float u   = fmaf(r, ahh[rt][reg] + brh, ahx[rt][reg]);
                const float eh  = __builtin_amdgcn_exp2f(fmaf(u, 2.f * l2e, bxh2));
                const float hc  = fmaf(-2.f, __builtin_amdgcn_rcpf(eh + 1.f), 1.f);
                const float hp = bf2f(sact[2][lidx]) + bf2f(sact[3][lidx]);
                const float hn = fmaf(z, hp - hc, hc);
                const size_t g = (size_t)row * DIM + c;
                const ushort_t hi = f2bf(hn);
                hbh[g] = hi;
                hbl[g] = f2bf(hn - bf2f(hi));
            }
        }
    }
}

#undef AS1
#undef AS3

// ===========================================================================
// Graph pooling + readout
// ===========================================================================
__global__ __launch_bounds__(256)
void pool_kernel(const ushort_t* __restrict__ hbh, const ushort_t* __restrict__ hbl,
                 const int* __restrict__ gid, float* __restrict__ pooled)
{
    const int idx = blockIdx.x * 256 + threadIdx.x;
    const int e = idx >> 7;
    const int n = idx & 127;
    const float hv = bf2f(hbh[idx]) + bf2f(hbl[idx]);
    atomicAdd(pooled + (size_t)gid[e] * DIM + n, hv);
}

__global__ __launch_bounds__(256)
void readout_kernel(const float* __restrict__ pooled,
                    const float* __restrict__ W1, const float* __restrict__ b1,
                    const float* __restrict__ W2, const float* __restrict__ b2,
                    const float* __restrict__ W3, const float* __restrict__ b3,
                    float* __restrict__ out)
{
    __shared__ float sp[DIM];
    __shared__ float s1[R_UNITS];
    __shared__ float s2[R_UNITS];
    const int g = blockIdx.x, tid = threadIdx.x;

    if (tid < DIM) sp[tid] = pooled[(size_t)g * DIM + tid];
    __syncthreads();

    float acc = b1[tid];
    for (int k = 0; k < DIM; k++) acc += sp[k] * W1[(size_t)k * R_UNITS + tid];
    s1[tid] = selu_f(acc);
    __syncthreads();

    acc = b2[tid];
    for (int k = 0; k < R_UNITS; k++) acc += s1[k] * W2[(size_t)k * R_UNITS + tid];
    s2[tid] = selu_f(acc) * W3[tid];
    __syncthreads();

    for (int s = 128; s > 0; s >>= 1) {
        if (tid < s) s2[tid] += s2[tid + s];
        __syncthreads();
    }
    if (tid == 0) out[g] = s2[0] + b3[0];
}

// ===========================================================================
extern "C" void kernel_launch(void* const* d_in, const int* in_sizes, int n_in,
                              void* d_out, int out_size, void* d_ws, size_t ws_size,
                              hipStream_t stream)
{
    const float* link_state = (const float*)d_in[0];
    const int*   gids       = (const int*)d_in[1];
    const int*   first      = (const int*)d_in[2];
    const int*   second     = (const int*)d_in[3];
    const float* Wmsg       = (const float*)d_in[5];
    const float* bmsg       = (const float*)d_in[6];
    const float* gK         = (const float*)d_in[7];
    const float* gU         = (const float*)d_in[8];
    const float* gbias      = (const float*)d_in[9];
    const float* W1         = (const float*)d_in[10];
    const float* b1         = (const float*)d_in[11];
    const float* W2         = (const float*)d_in[12];
    const float* b2         = (const float*)d_in[13];
    const float* W3         = (const float*)d_in[14];
    const float* b3         = (const float*)d_in[15];
    float* out = (float*)d_out;

    // ws layout (16B-aligned segments):
    //   offsets[100004] counts[1e5] cursor[1e5] bsum[128] sfirst[P] ssecond[P]
    //   wt[32768 us] wy[32768 us] wb[196608 us]
    //   hb_hi[E*128 us] hb_lo[E*128 us] agg_hi[E*128 us] agg_lo[E*128 us]
    //   Gregion[E*128 f32] (fp16 G uses first half) Y2b[E*128 f32]
    int* offsets = (int*)d_ws;
    int* counts  = offsets + 100004;
    int* cursor  = counts + E_NUM;
    int* bsum    = cursor + E_NUM;
    int* sfirst  = bsum + 128;
    int* ssecond = sfirst + P_NUM;
    ushort_t* wt     = (ushort_t*)(ssecond + P_NUM);
    ushort_t* wy     = wt + 32768;
    ushort_t* wb     = wy + 32768;
    ushort_t* hb_hi  = wb + 196608;
    ushort_t* hb_lo  = hb_hi + (size_t)E_NUM * DIM;
    ushort_t* agg_hi = hb_lo + (size_t)E_NUM * DIM;
    ushort_t* agg_lo = agg_hi + (size_t)E_NUM * DIM;
    float*    Gf     = (float*)(agg_lo + (size_t)E_NUM * DIM);   // region
    __half*   Gh     = (__half*)Gf;                              // fp16 alias
    float*    Y2b    = Gf + (size_t)E_NUM * DIM;

    // ---- one-time prep ----
    hipMemsetAsync(counts, 0, E_NUM * sizeof(int), stream);
    hipMemsetAsync(cursor, 0, E_NUM * sizeof(int), stream);
    hist_kernel<<<P_NUM / 256, 256, 0, stream>>>(second, counts);
    scanA_kernel<<<98, 1024, 0, stream>>>(counts, offsets, bsum);
    scanB_kernel<<<1, 1, 0, stream>>>(bsum, offsets);
    scanC_kernel<<<98, 1024, 0, stream>>>(offsets, bsum);
    fill_kernel<<<P_NUM / 256, 256, 0, stream>>>(first, second, offsets, cursor,
                                                 sfirst, ssecond);
    wsplit_build_kernel<<<32, 256, 0, stream>>>(Wmsg, wt, wy);
    wb_build_kernel<<<96, 256, 0, stream>>>(gK, gU, wb);
    cast_h_kernel<<<(E_NUM * DIM) / 256, 256, 0, stream>>>(link_state, hb_hi, hb_lo);

    // ---- message-passing steps ----
    for (int t = 0; t < T_STEPS; t++) {
        gy_kernel<<<E_NUM / 32, 256, 0, stream>>>(hb_hi, hb_lo, wt, wy, bmsg,
                                                  Gh, Y2b);
        agg_csr_kernel<<<E_NUM / 32, 256, 0, stream>>>((const __half2*)Gh, Y2b,
                                                       offsets, sfirst,
                                                       agg_hi, agg_lo);
        gru_kernel<<<(E_NUM + 63) / 64, 512, 0, stream>>>(agg_hi, agg_lo,
                                                          hb_hi, hb_lo,
                                                          wb, gbias);
    }

    // ---- pool + readout (G region reused as pooled buffer) ----
    float* pooled = Gf;
    hipMemsetAsync(pooled, 0, (size_t)G_NUM * DIM * sizeof(float), stream);
    pool_kernel<<<(E_NUM * DIM) / 256, 256, 0, stream>>>(hb_hi, hb_lo, gids, pooled);
    readout_kernel<<<G_NUM, 256, 0, stream>>>(pooled, W1, b1, W2, b2, W3, b3, out);
}

// Round 12
// 1677.215 us; speedup vs baseline: 1.1038x; 1.1038x over previous
//
#include <hip/hip_runtime.h>
#include <hip/hip_fp16.h>
#include <math.h>

#define DIM 128
#define E_NUM 100000
#define P_NUM 800000
#define G_NUM 1000
#define T_STEPS 8
#define R_UNITS 256

typedef __attribute__((ext_vector_type(8))) short bf16x8;   // 8 bf16 = 4 VGPRs
typedef __attribute__((ext_vector_type(4))) float f32x4;    // 16x16 MFMA acc

typedef unsigned short ushort_t;
typedef unsigned int   uint_t;

__device__ __forceinline__ float selu_f(float x) {
    const float alpha = 1.6732632423543772f;
    const float scale = 1.0507009873554805f;
    return x > 0.f ? scale * x : scale * alpha * expm1f(x);
}

// Fast selu: A*exp2(x*log2e)-A instead of libm expm1f.
__device__ __forceinline__ float selu_fast(float x) {
    const float scale = 1.0507009873554805f;
    const float A     = 1.7580993408473766f;    // scale*alpha
    const float l2e   = 1.4426950408889634f;
    const float e = __builtin_amdgcn_exp2f(x * l2e);
    return x > 0.f ? scale * x : A * e - A;
}

__device__ __forceinline__ ushort_t f2bf(float x) {
    uint_t u = __float_as_uint(x);
    uint_t r = (u + 0x7fffu + ((u >> 16) & 1u)) >> 16;
    return (ushort_t)r;
}
__device__ __forceinline__ float bf2f(ushort_t h) {
    return __uint_as_float(((uint_t)h) << 16);
}

// ===========================================================================
// CSR build (once per launch). Multi-block scan.
// ===========================================================================
__global__ __launch_bounds__(256)
void hist_kernel(const int* __restrict__ second, int* __restrict__ counts)
{
    const int p = blockIdx.x * 256 + threadIdx.x;
    atomicAdd(&counts[second[p]], 1);
}

__global__ __launch_bounds__(1024)
void scanA_kernel(const int* __restrict__ counts, int* __restrict__ offsets,
                  int* __restrict__ bsum)
{
    __shared__ int buf[1024];
    const int i = blockIdx.x * 1024 + threadIdx.x;
    const int v = (i < E_NUM) ? counts[i] : 0;
    buf[threadIdx.x] = v;
    __syncthreads();
    for (int off = 1; off < 1024; off <<= 1) {
        const int t = (threadIdx.x >= off) ? buf[threadIdx.x - off] : 0;
        __syncthreads();
        buf[threadIdx.x] += t;
        __syncthreads();
    }
    if (i < E_NUM) offsets[i] = buf[threadIdx.x] - v;   // block-local exclusive
    if (threadIdx.x == 1023) bsum[blockIdx.x] = buf[1023];
}

__global__ void scanB_kernel(int* __restrict__ bsum, int* __restrict__ offsets)
{
    int acc = 0;
    for (int b = 0; b < 98; b++) { const int t = bsum[b]; bsum[b] = acc; acc += t; }
    offsets[E_NUM] = P_NUM;
}

__global__ __launch_bounds__(1024)
void scanC_kernel(int* __restrict__ offsets, const int* __restrict__ bsum)
{
    const int i = blockIdx.x * 1024 + threadIdx.x;
    if (i < E_NUM) offsets[i] += bsum[blockIdx.x];
}

__global__ __launch_bounds__(256)
void fill_kernel(const int* __restrict__ first, const int* __restrict__ second,
                 const int* __restrict__ offsets, int* __restrict__ cursor,
                 int* __restrict__ sfirst, int* __restrict__ ssecond)
{
    const int p = blockIdx.x * 256 + threadIdx.x;
    const int d = second[p];
    const int pos = atomicAdd(&cursor[d], 1);
    const int idx = offsets[d] + pos;
    sfirst[idx] = first[p];
    ssecond[idx] = d;
}

// ===========================================================================
// One-time prep (unchanged).
// ===========================================================================
__global__ __launch_bounds__(256)
void cast_h_kernel(const float* __restrict__ src,
                   ushort_t* __restrict__ dhi, ushort_t* __restrict__ dlo)
{
    const int idx = blockIdx.x * 256 + threadIdx.x;
    const float x = src[idx];
    const ushort_t hi = f2bf(x);
    dhi[idx] = hi;
    dlo[idx] = f2bf(x - bf2f(hi));
}

__global__ __launch_bounds__(256)
void wsplit_build_kernel(const float* __restrict__ Wmsg,
                         ushort_t* __restrict__ wt, ushort_t* __restrict__ wy)
{
    const int idx  = blockIdx.x * 256 + threadIdx.x;   // 8192 slots (2 halves)
    const int lane = idx & 63;
    const int nt   = (idx >> 6) & 7;
    const int comp = (idx >> 9) & 1;
    const int ks   = (idx >> 10) & 3;
    const int half = idx >> 12;
    const int n    = nt * 16 + (lane & 15);
    const int kb   = ks * 32 + (lane >> 4) * 8 + half * 128;
    ushort_t* dst  = half ? wy : wt;
    const int slot = idx & 4095;
#pragma unroll
    for (int j = 0; j < 8; j++) {
        const float w = Wmsg[(size_t)(kb + j) * DIM + n];
        const ushort_t hi = f2bf(w);
        dst[(size_t)slot * 8 + j] = comp ? f2bf(w - bf2f(hi)) : hi;
    }
}

__global__ __launch_bounds__(256)
void wb_build_kernel(const float* __restrict__ K, const float* __restrict__ U,
                     ushort_t* __restrict__ wb)
{
    const int idx  = blockIdx.x * 256 + threadIdx.x;   // 24576 slots
    const int lane = idx & 63;
    int t = idx >> 6;
    const int nt   = t % 24;  t /= 24;
    const int comp = t & 1;   t >>= 1;
    const int gemm = t & 1;
    const int ks   = t >> 1;
    const float* src = gemm ? U : K;
    const int n  = nt * 16 + (lane & 15);
    const int kb = ks * 32 + (lane >> 4) * 8;
#pragma unroll
    for (int j = 0; j < 8; j++) {
        const float w = src[(size_t)(kb + j) * 384 + n];
        const ushort_t hi = f2bf(w);
        wb[(size_t)idx * 8 + j] = comp ? f2bf(w - bf2f(hi)) : hi;
    }
}

// ===========================================================================
// GY kernel (R17 structure, R23 fp16-G output kept).
// ===========================================================================
#define AS1(p) ((const __attribute__((address_space(1))) unsigned int*)(p))
#define AS3(p) ((__attribute__((address_space(3))) unsigned int*)(p))

__global__ __launch_bounds__(256, 4)
void gy_kernel(const ushort_t* __restrict__ hbh, const ushort_t* __restrict__ hbl,
               const ushort_t* __restrict__ wt, const ushort_t* __restrict__ wy,
               const float* __restrict__ bmsg,
               __half* __restrict__ Gh, float* __restrict__ Y2b)
{
    __shared__ __align__(16) ushort_t sact[2][4096];   // hh, hl (8KB each)

    const int tid  = threadIdx.x;
    const int lane = tid & 63;
    const int w    = tid >> 6;
    const int e0   = blockIdx.x * 32;
    const int m16  = lane & 15;
    const int quad = lane >> 4;

    // stage acts in fragment order: granule g = gk*128 + gq*32 + gr*16 + gm
#pragma unroll
    for (int i = 0; i < 2; i++) {
        const int g  = tid + i * 256;
        const int gm = g & 15;
        const int gr = (g >> 4) & 1;
        const int gq = (g >> 5) & 3;
        const int gk = g >> 7;
        const size_t soff = (size_t)(e0 + gr * 16 + gm) * DIM + gk * 32 + gq * 8;
        __builtin_amdgcn_global_load_lds(AS1(hbh + soff), AS3((char*)sact[0] + g * 16), 16, 0, 0);
        __builtin_amdgcn_global_load_lds(AS1(hbl + soff), AS3((char*)sact[1] + g * 16), 16, 0, 0);
    }
    __syncthreads();   // single prologue drain

#define ACT(a_, ks_, rt_) \
    (*(const bf16x8*)((const char*)sact[a_] + (size_t)((ks_) * 2048 + quad * 512 + (rt_) * 256 + m16 * 16)))

    f32x4 acc[2][4] = {};
#pragma unroll
    for (int ks = 0; ks < 4; ks++) {
        bf16x8 ah[2], al[2];
#pragma unroll
        for (int rt = 0; rt < 2; rt++) {
            ah[rt] = ACT(0, ks, rt);
            al[rt] = ACT(1, ks, rt);
        }
#pragma unroll
        for (int ntl = 0; ntl < 4; ntl++) {
            const int ntg = w * 4 + ntl;                    // 0..15
            const ushort_t* wsel = (ntg < 8) ? wt : wy;
            const int nt = ntg & 7;
            const bf16x8 bh = *(const bf16x8*)(wsel + (size_t)(((ks * 2 + 0) * 8 + nt) * 64 + lane) * 8);
            const bf16x8 bl = *(const bf16x8*)(wsel + (size_t)(((ks * 2 + 1) * 8 + nt) * 64 + lane) * 8);
#pragma unroll
            for (int rt = 0; rt < 2; rt++) {
                acc[rt][ntl] = __builtin_amdgcn_mfma_f32_16x16x32_bf16(ah[rt], bh, acc[rt][ntl], 0, 0, 0);
                acc[rt][ntl] = __builtin_amdgcn_mfma_f32_16x16x32_bf16(al[rt], bh, acc[rt][ntl], 0, 0, 0);
                acc[rt][ntl] = __builtin_amdgcn_mfma_f32_16x16x32_bf16(ah[rt], bl, acc[rt][ntl], 0, 0, 0);
            }
        }
    }
#undef ACT
    // C layout: col = lane&15, row = quad*4 + reg
#pragma unroll
    for (int ntl = 0; ntl < 4; ntl++) {
        const int ntg = w * 4 + ntl;
        const int c   = (ntg & 7) * 16 + m16;               // 0..127 within half
        if (ntg < 8) {
            // G half: store fp16 (gather-path compression)
#pragma unroll
            for (int rt = 0; rt < 2; rt++) {
#pragma unroll
                for (int reg = 0; reg < 4; reg++) {
                    const size_t row = (size_t)(e0 + rt * 16 + quad * 4 + reg);
                    Gh[row * DIM + c] = __float2half_rn(acc[rt][ntl][reg]);
                }
            }
        } else {
            const float bb = bmsg[c];
#pragma unroll
            for (int rt = 0; rt < 2; rt++) {
#pragma unroll
                for (int reg = 0; reg < 4; reg++) {
                    const size_t row = (size_t)(e0 + rt * 16 + quad * 4 + reg);
                    Y2b[row * DIM + c] = acc[rt][ntl][reg] + bb;
                }
            }
        }
    }
}

// ===========================================================================
// Fused AGG+GRU kernel, R25.
//
// R24 post-mortem: rt=4 regressed again (occupancy 21%) -> R23's gru config
// is the operating point; weight traffic is NOT the gate. The remaining
// structural waste: agg wrote 51MB (agg_hi/lo) to HBM and gru DMA'd the
// same 51MB straight back. The producer/consumer blocks are row-aligned
// (agg's 32 dests == gru's 32-row tile), so fuse:
//   phase 0: issue hh/hl DMA (as R23 gru)
//   phase 1: agg for this block's 32 rows -- 8 waves x 4 dests, per-dest
//            math/order identical to R23 (bit-identical x); hi/lo split
//            written DIRECTLY into LDS at gru's fragment positions
//   one __syncthreads (drains DMA under ~60us of agg cover)
//   phase 2: R23 gru MFMA + epilogue, verbatim (x read from LDS)
// Saves 102MB/step round-trip + 8 launches. No tail (3125*32=100000).
// ===========================================================================
__device__ __forceinline__ void aggru_one_dest(
    const __half2* __restrict__ Gh2, const int* __restrict__ sfirst,
    ushort_t* __restrict__ sxh, ushort_t* __restrict__ sxl,
    int rrel, int start, int end, float2 y, int c2, int lane)
{
    float a0 = 0.f, a1 = 0.f;
    int p = start;
    for (; p + 8 <= end; p += 8) {
        int f[8];
#pragma unroll
        for (int j = 0; j < 8; j++) f[j] = sfirst[p + j];
        __half2 g[8];
#pragma unroll
        for (int j = 0; j < 8; j++)
            g[j] = Gh2[(size_t)f[j] * 64 + lane];
#pragma unroll
        for (int j = 0; j < 8; j++) {
            const float2 gf = __half22float2(g[j]);
            a0 += selu_fast(gf.x + y.x);
            a1 += selu_fast(gf.y + y.y);
        }
    }
    if (p + 4 <= end) {
        int f[4];
#pragma unroll
        for (int j = 0; j < 4; j++) f[j] = sfirst[p + j];
        __half2 g[4];
#pragma unroll
        for (int j = 0; j < 4; j++)
            g[j] = Gh2[(size_t)f[j] * 64 + lane];
#pragma unroll
        for (int j = 0; j < 4; j++) {
            const float2 gf = __half22float2(g[j]);
            a0 += selu_fast(gf.x + y.x);
            a1 += selu_fast(gf.y + y.y);
        }
        p += 4;
    }
    for (; p < end; p++) {
        const int f = sfirst[p];
        const float2 gf = __half22float2(Gh2[(size_t)f * 64 + lane]);
        a0 += selu_fast(gf.x + y.x);
        a1 += selu_fast(gf.y + y.y);
    }
    // hi/lo split -> LDS fragment position (ushort idx base, elem even)
    const int ks = c2 >> 5;
    const int qd = (c2 >> 3) & 3;
    const int el = c2 & 7;
    const int base = (ks * 128 + qd * 32 + (rrel >> 4) * 16 + (rrel & 15)) * 8 + el;
    const ushort_t h0 = f2bf(a0);
    const ushort_t h1 = f2bf(a1);
    ushort2 hv, lv;
    hv.x = h0;  hv.y = h1;
    lv.x = f2bf(a0 - bf2f(h0));
    lv.y = f2bf(a1 - bf2f(h1));
    *(ushort2*)(sxh + base) = hv;
    *(ushort2*)(sxl + base) = lv;
}

__global__ __launch_bounds__(512, 4)
void aggru_kernel(const __half2* __restrict__ Gh2, const float* __restrict__ Y2b,
                  const int* __restrict__ offsets, const int* __restrict__ sfirst,
                  ushort_t* __restrict__ hbh, ushort_t* __restrict__ hbl,
                  const ushort_t* __restrict__ wb, const float* __restrict__ bias)
{
    __shared__ __align__(16) ushort_t sact[4][4096];   // xh, xl, hh, hl (8KB each)

    const int tid  = threadIdx.x;
    const int lane = tid & 63;
    const int w    = tid >> 6;          // 0..7
    const int e0   = blockIdx.x * 32;
    const int m16  = lane & 15;
    const int quad = lane >> 4;

    // ---- phase 0: stage hh/hl in fragment order (granule = tid) ----
    {
        const int gm = tid & 15;
        const int gr = (tid >> 4) & 1;
        const int gq = (tid >> 5) & 3;
        const int gk = tid >> 7;
        const size_t soff = (size_t)(e0 + gr * 16 + gm) * DIM + gk * 32 + gq * 8;
        __builtin_amdgcn_global_load_lds(AS1(hbh + soff), AS3((char*)sact[2] + tid * 16), 16, 0, 0);
        __builtin_amdgcn_global_load_lds(AS1(hbl + soff), AS3((char*)sact[3] + tid * 16), 16, 0, 0);
    }

    // ---- phase 1: agg for this block's rows; x written into LDS ----
    {
        const int c2 = lane * 2;
        const int d0 = e0 + w * 4;
        const int o0 = offsets[d0 + 0], o1 = offsets[d0 + 1];
        const int o2 = offsets[d0 + 2], o3 = offsets[d0 + 3], o4 = offsets[d0 + 4];
        const float2* Yp = (const float2*)(Y2b + (size_t)d0 * DIM + c2);
        const float2 y0 = Yp[0], y1 = Yp[64], y2 = Yp[128], y3 = Yp[192];
        const int r0 = w * 4;
        aggru_one_dest(Gh2, sfirst, sact[0], sact[1], r0 + 0, o0, o1, y0, c2, lane);
        aggru_one_dest(Gh2, sfirst, sact[0], sact[1], r0 + 1, o1, o2, y1, c2, lane);
        aggru_one_dest(Gh2, sfirst, sact[0], sact[1], r0 + 2, o2, o3, y2, c2, lane);
        aggru_one_dest(Gh2, sfirst, sact[0], sact[1], r0 + 3, o3, o4, y3, c2, lane);
    }
    __syncthreads();   // x LDS-visible + DMA drained (covered by agg phase)

    // ---- phase 2: GRU MFMA + epilogue (R23 verbatim) ----
    f32x4 az[2] = {}, ar[2] = {}, ahx[2] = {}, ahh[2] = {};

#define WB(ks_, gm_, cp_, nt_) \
    (*(const bf16x8*)(wb + ((size_t)(((ks_) * 96) + (gm_) * 48 + (cp_) * 24 + (nt_)) * 64 + lane) * 8))
#define ACT(a_, ks_, rt_) \
    (*(const bf16x8*)((const char*)sact[a_] + (size_t)((ks_) * 2048 + quad * 512 + (rt_) * 256 + m16 * 16)))

#pragma unroll
    for (int ks = 0; ks < 4; ks++) {
        const bf16x8 KzH = WB(ks, 0, 0, w),      KzL = WB(ks, 0, 1, w);
        const bf16x8 UzH = WB(ks, 1, 0, w),      UzL = WB(ks, 1, 1, w);
        const bf16x8 KrH = WB(ks, 0, 0, w + 8),  KrL = WB(ks, 0, 1, w + 8);
        const bf16x8 UrH = WB(ks, 1, 0, w + 8),  UrL = WB(ks, 1, 1, w + 8);
        const bf16x8 KhH = WB(ks, 0, 0, w + 16), KhL = WB(ks, 0, 1, w + 16);
        const bf16x8 UhH = WB(ks, 1, 0, w + 16), UhL = WB(ks, 1, 1, w + 16);
#pragma unroll
        for (int rt = 0; rt < 2; rt++) {
            const bf16x8 xh = ACT(0, ks, rt);
            const bf16x8 xl = ACT(1, ks, rt);
            const bf16x8 hh = ACT(2, ks, rt);
            const bf16x8 hl = ACT(3, ks, rt);

            az[rt] = __builtin_amdgcn_mfma_f32_16x16x32_bf16(xh, KzH, az[rt], 0, 0, 0);
            az[rt] = __builtin_amdgcn_mfma_f32_16x16x32_bf16(xl, KzH, az[rt], 0, 0, 0);
            az[rt] = __builtin_amdgcn_mfma_f32_16x16x32_bf16(xh, KzL, az[rt], 0, 0, 0);
            az[rt] = __builtin_amdgcn_mfma_f32_16x16x32_bf16(hh, UzH, az[rt], 0, 0, 0);
            az[rt] = __builtin_amdgcn_mfma_f32_16x16x32_bf16(hl, UzH, az[rt], 0, 0, 0);
            az[rt] = __builtin_amdgcn_mfma_f32_16x16x32_bf16(hh, UzL, az[rt], 0, 0, 0);

            ar[rt] = __builtin_amdgcn_mfma_f32_16x16x32_bf16(xh, KrH, ar[rt], 0, 0, 0);
            ar[rt] = __builtin_amdgcn_mfma_f32_16x16x32_bf16(xl, KrH, ar[rt], 0, 0, 0);
            ar[rt] = __builtin_amdgcn_mfma_f32_16x16x32_bf16(xh, KrL, ar[rt], 0, 0, 0);
            ar[rt] = __builtin_amdgcn_mfma_f32_16x16x32_bf16(hh, UrH, ar[rt], 0, 0, 0);
            ar[rt] = __builtin_amdgcn_mfma_f32_16x16x32_bf16(hl, UrH, ar[rt], 0, 0, 0);
            ar[rt] = __builtin_amdgcn_mfma_f32_16x16x32_bf16(hh, UrL, ar[rt], 0, 0, 0);

            ahx[rt] = __builtin_amdgcn_mfma_f32_16x16x32_bf16(xh, KhH, ahx[rt], 0, 0, 0);
            ahx[rt] = __builtin_amdgcn_mfma_f32_16x16x32_bf16(xl, KhH, ahx[rt], 0, 0, 0);
            ahx[rt] = __builtin_amdgcn_mfma_f32_16x16x32_bf16(xh, KhL, ahx[rt], 0, 0, 0);
            ahh[rt] = __builtin_amdgcn_mfma_f32_16x16x32_bf16(hh, UhH, ahh[rt], 0, 0, 0);
            ahh[rt] = __builtin_amdgcn_mfma_f32_16x16x32_bf16(hl, UhH, ahh[rt], 0, 0, 0);
            ahh[rt] = __builtin_amdgcn_mfma_f32_16x16x32_bf16(hh, UhL, ahh[rt], 0, 0, 0);
        }
    }
#undef WB
#undef ACT

    const int c = w * 16 + m16;
    const float l2e  = 1.4426950408889634f;
    const float bzn  = -(bias[c] + bias[384 + c]) * l2e;          // pre-scaled
    const float brn  = -(bias[128 + c] + bias[512 + c]) * l2e;
    const float bxh  = bias[256 + c];
    const float brh  = bias[640 + c];
    const float bxh2 = bxh * (2.f * l2e);

    // h_prev from the staged LDS copy (pre-update bits, exact):
    const int ksc   = w >> 1;
    const int quadc = (2 * w + (m16 >> 3)) & 3;
    const int elem  = m16 & 7;

#pragma unroll
    for (int rt = 0; rt < 2; rt++) {
#pragma unroll
        for (int reg = 0; reg < 4; reg++) {
            const int rrel = rt * 16 + quad * 4 + reg;
            const int row  = e0 + rrel;
            const int lidx = (ksc * 128 + quadc * 32 + rt * 16 + (quad * 4 + reg)) * 8 + elem;
            // sigmoid via exp2+rcp (bias pre-folded with -log2e)
            const float z = __builtin_amdgcn_rcpf(
                1.f + __builtin_amdgcn_exp2f(fmaf(az[rt][reg], -l2e, bzn)));
            const float r = __builtin_amdgcn_rcpf(
                1.f + __builtin_amdgcn_exp2f(fmaf(ar[rt][reg], -l2e, brn)));
            // tanh(s) = 1 - 2/(exp2(2*l2e*s)+1); s = ahx+bxh + r*(ahh+brh)
            const float u   = fmaf(r, ahh[rt][reg] + brh, ahx[rt][reg]);
            const float eh  = __builtin_amdgcn_exp2f(fmaf(u, 2.f * l2e, bxh2));
            const float hc  = fmaf(-2.f, __builtin_amdgcn_rcpf(eh + 1.f), 1.f);
            const float hp = bf2f(sact[2][lidx]) + bf2f(sact[3][lidx]);
            const float hn = fmaf(z, hp - hc, hc);
            const size_t g = (size_t)row * DIM + c;
            const ushort_t hi = f2bf(hn);
            hbh[g] = hi;
            hbl[g] = f2bf(hn - bf2f(hi));
        }
    }
}

#undef AS1
#undef AS3

// ===========================================================================
// Graph pooling + readout
// ===========================================================================
__global__ __launch_bounds__(256)
void pool_kernel(const ushort_t* __restrict__ hbh, const ushort_t* __restrict__ hbl,
                 const int* __restrict__ gid, float* __restrict__ pooled)
{
    const int idx = blockIdx.x * 256 + threadIdx.x;
    const int e = idx >> 7;
    const int n = idx & 127;
    const float hv = bf2f(hbh[idx]) + bf2f(hbl[idx]);
    atomicAdd(pooled + (size_t)gid[e] * DIM + n, hv);
}

__global__ __launch_bounds__(256)
void readout_kernel(const float* __restrict__ pooled,
                    const float* __restrict__ W1, const float* __restrict__ b1,
                    const float* __restrict__ W2, const float* __restrict__ b2,
                    const float* __restrict__ W3, const float* __restrict__ b3,
                    float* __restrict__ out)
{
    __shared__ float sp[DIM];
    __shared__ float s1[R_UNITS];
    __shared__ float s2[R_UNITS];
    const int g = blockIdx.x, tid = threadIdx.x;

    if (tid < DIM) sp[tid] = pooled[(size_t)g * DIM + tid];
    __syncthreads();

    float acc = b1[tid];
    for (int k = 0; k < DIM; k++) acc += sp[k] * W1[(size_t)k * R_UNITS + tid];
    s1[tid] = selu_f(acc);
    __syncthreads();

    acc = b2[tid];
    for (int k = 0; k < R_UNITS; k++) acc += s1[k] * W2[(size_t)k * R_UNITS + tid];
    s2[tid] = selu_f(acc) * W3[tid];
    __syncthreads();

    for (int s = 128; s > 0; s >>= 1) {
        if (tid < s) s2[tid] += s2[tid + s];
        __syncthreads();
    }
    if (tid == 0) out[g] = s2[0] + b3[0];
}

// ===========================================================================
extern "C" void kernel_launch(void* const* d_in, const int* in_sizes, int n_in,
                              void* d_out, int out_size, void* d_ws, size_t ws_size,
                              hipStream_t stream)
{
    const float* link_state = (const float*)d_in[0];
    const int*   gids       = (const int*)d_in[1];
    const int*   first      = (const int*)d_in[2];
    const int*   second     = (const int*)d_in[3];
    const float* Wmsg       = (const float*)d_in[5];
    const float* bmsg       = (const float*)d_in[6];
    const float* gK         = (const float*)d_in[7];
    const float* gU         = (const float*)d_in[8];
    const float* gbias      = (const float*)d_in[9];
    const float* W1         = (const float*)d_in[10];
    const float* b1         = (const float*)d_in[11];
    const float* W2         = (const float*)d_in[12];
    const float* b2         = (const float*)d_in[13];
    const float* W3         = (const float*)d_in[14];
    const float* b3         = (const float*)d_in[15];
    float* out = (float*)d_out;

    // ws layout (16B-aligned segments):
    //   offsets[100004] counts[1e5] cursor[1e5] bsum[128] sfirst[P] ssecond[P]
    //   wt[32768 us] wy[32768 us] wb[196608 us]
    //   hb_hi[E*128 us] hb_lo[E*128 us] (agg buffers now unused)
    //   Gregion[E*128 f32] (fp16 G uses first half) Y2b[E*128 f32]
    int* offsets = (int*)d_ws;
    int* counts  = offsets + 100004;
    int* cursor  = counts + E_NUM;
    int* bsum    = cursor + E_NUM;
    int* sfirst  = bsum + 128;
    int* ssecond = sfirst + P_NUM;
    ushort_t* wt     = (ushort_t*)(ssecond + P_NUM);
    ushort_t* wy     = wt + 32768;
    ushort_t* wb     = wy + 32768;
    ushort_t* hb_hi  = wb + 196608;
    ushort_t* hb_lo  = hb_hi + (size_t)E_NUM * DIM;
    ushort_t* agg_hi = hb_lo + (size_t)E_NUM * DIM;   // unused (kept for layout)
    ushort_t* agg_lo = agg_hi + (size_t)E_NUM * DIM;  // unused
    float*    Gf     = (float*)(agg_lo + (size_t)E_NUM * DIM);   // region
    __half*   Gh     = (__half*)Gf;                              // fp16 alias
    float*    Y2b    = Gf + (size_t)E_NUM * DIM;

    // ---- one-time prep ----
    hipMemsetAsync(counts, 0, E_NUM * sizeof(int), stream);
    hipMemsetAsync(cursor, 0, E_NUM * sizeof(int), stream);
    hist_kernel<<<P_NUM / 256, 256, 0, stream>>>(second, counts);
    scanA_kernel<<<98, 1024, 0, stream>>>(counts, offsets, bsum);
    scanB_kernel<<<1, 1, 0, stream>>>(bsum, offsets);
    scanC_kernel<<<98, 1024, 0, stream>>>(offsets, bsum);
    fill_kernel<<<P_NUM / 256, 256, 0, stream>>>(first, second, offsets, cursor,
                                                 sfirst, ssecond);
    wsplit_build_kernel<<<32, 256, 0, stream>>>(Wmsg, wt, wy);
    wb_build_kernel<<<96, 256, 0, stream>>>(gK, gU, wb);
    cast_h_kernel<<<(E_NUM * DIM) / 256, 256, 0, stream>>>(link_state, hb_hi, hb_lo);

    // ---- message-passing steps ----
    for (int t = 0; t < T_STEPS; t++) {
        gy_kernel<<<E_NUM / 32, 256, 0, stream>>>(hb_hi, hb_lo, wt, wy, bmsg,
                                                  Gh, Y2b);
        aggru_kernel<<<E_NUM / 32, 512, 0, stream>>>((const __half2*)Gh, Y2b,
                                                     offsets, sfirst,
                                                     hb_hi, hb_lo,
                                                     wb, gbias);
    }

    // ---- pool + readout (G region reused as pooled buffer) ----
    float* pooled = Gf;
    hipMemsetAsync(pooled, 0, (size_t)G_NUM * DIM * sizeof(float), stream);
    pool_kernel<<<(E_NUM * DIM) / 256, 256, 0, stream>>>(hb_hi, hb_lo, gids, pooled);
    readout_kernel<<<G_NUM, 256, 0, stream>>>(pooled, W1, b1, W2, b2, W3, b3, out);
}

// Round 14
// 1593.575 us; speedup vs baseline: 1.1617x; 1.0525x over previous
//
#include <hip/hip_runtime.h>
#include <hip/hip_fp16.h>
#include <math.h>

#define DIM 128
#define E_NUM 100000
#define P_NUM 800000
#define G_NUM 1000
#define T_STEPS 8
#define R_UNITS 256

typedef __attribute__((ext_vector_type(8))) short bf16x8;   // 8 bf16 = 4 VGPRs
typedef __attribute__((ext_vector_type(4))) float f32x4;    // 16x16 MFMA acc

typedef unsigned short ushort_t;
typedef unsigned int   uint_t;

__device__ __forceinline__ float selu_f(float x) {
    const float alpha = 1.6732632423543772f;
    const float scale = 1.0507009873554805f;
    return x > 0.f ? scale * x : scale * alpha * expm1f(x);
}

// Fast selu: A*exp2(x*log2e)-A instead of libm expm1f.
__device__ __forceinline__ float selu_fast(float x) {
    const float scale = 1.0507009873554805f;
    const float A     = 1.7580993408473766f;    // scale*alpha
    const float l2e   = 1.4426950408889634f;
    const float e = __builtin_amdgcn_exp2f(x * l2e);
    return x > 0.f ? scale * x : A * e - A;
}

__device__ __forceinline__ ushort_t f2bf(float x) {
    uint_t u = __float_as_uint(x);
    uint_t r = (u + 0x7fffu + ((u >> 16) & 1u)) >> 16;
    return (ushort_t)r;
}
__device__ __forceinline__ float bf2f(ushort_t h) {
    return __uint_as_float(((uint_t)h) << 16);
}

// ===========================================================================
// CSR build (once per launch). Multi-block scan.
// ===========================================================================
__global__ __launch_bounds__(256)
void hist_kernel(const int* __restrict__ second, int* __restrict__ counts)
{
    const int p = blockIdx.x * 256 + threadIdx.x;
    atomicAdd(&counts[second[p]], 1);
}

__global__ __launch_bounds__(1024)
void scanA_kernel(const int* __restrict__ counts, int* __restrict__ offsets,
                  int* __restrict__ bsum)
{
    __shared__ int buf[1024];
    const int i = blockIdx.x * 1024 + threadIdx.x;
    const int v = (i < E_NUM) ? counts[i] : 0;
    buf[threadIdx.x] = v;
    __syncthreads();
    for (int off = 1; off < 1024; off <<= 1) {
        const int t = (threadIdx.x >= off) ? buf[threadIdx.x - off] : 0;
        __syncthreads();
        buf[threadIdx.x] += t;
        __syncthreads();
    }
    if (i < E_NUM) offsets[i] = buf[threadIdx.x] - v;   // block-local exclusive
    if (threadIdx.x == 1023) bsum[blockIdx.x] = buf[1023];
}

__global__ void scanB_kernel(int* __restrict__ bsum, int* __restrict__ offsets)
{
    int acc = 0;
    for (int b = 0; b < 98; b++) { const int t = bsum[b]; bsum[b] = acc; acc += t; }
    offsets[E_NUM] = P_NUM;
}

__global__ __launch_bounds__(1024)
void scanC_kernel(int* __restrict__ offsets, const int* __restrict__ bsum)
{
    const int i = blockIdx.x * 1024 + threadIdx.x;
    if (i < E_NUM) offsets[i] += bsum[blockIdx.x];
}

__global__ __launch_bounds__(256)
void fill_kernel(const int* __restrict__ first, const int* __restrict__ second,
                 const int* __restrict__ offsets, int* __restrict__ cursor,
                 int* __restrict__ sfirst, int* __restrict__ ssecond)
{
    const int p = blockIdx.x * 256 + threadIdx.x;
    const int d = second[p];
    const int pos = atomicAdd(&cursor[d], 1);
    const int idx = offsets[d] + pos;
    sfirst[idx] = first[p];
    ssecond[idx] = d;
}

// ===========================================================================
// One-time prep (R25 versions: full hi/lo weight tables -- R26's hi-only
// variant FAILED numerics: bf16 weight rounding is a systematic operator
// perturbation amplified by the 8-step recurrence).
// ===========================================================================
__global__ __launch_bounds__(256)
void cast_h_kernel(const float* __restrict__ src,
                   ushort_t* __restrict__ dhi, ushort_t* __restrict__ dlo)
{
    const int idx = blockIdx.x * 256 + threadIdx.x;
    const float x = src[idx];
    const ushort_t hi = f2bf(x);
    dhi[idx] = hi;
    dlo[idx] = f2bf(x - bf2f(hi));
}

__global__ __launch_bounds__(256)
void wsplit_build_kernel(const float* __restrict__ Wmsg,
                         ushort_t* __restrict__ wt, ushort_t* __restrict__ wy)
{
    const int idx  = blockIdx.x * 256 + threadIdx.x;   // 8192 slots (2 halves)
    const int lane = idx & 63;
    const int nt   = (idx >> 6) & 7;
    const int comp = (idx >> 9) & 1;
    const int ks   = (idx >> 10) & 3;
    const int half = idx >> 12;
    const int n    = nt * 16 + (lane & 15);
    const int kb   = ks * 32 + (lane >> 4) * 8 + half * 128;
    ushort_t* dst  = half ? wy : wt;
    const int slot = idx & 4095;
#pragma unroll
    for (int j = 0; j < 8; j++) {
        const float w = Wmsg[(size_t)(kb + j) * DIM + n];
        const ushort_t hi = f2bf(w);
        dst[(size_t)slot * 8 + j] = comp ? f2bf(w - bf2f(hi)) : hi;
    }
}

__global__ __launch_bounds__(256)
void wb_build_kernel(const float* __restrict__ K, const float* __restrict__ U,
                     ushort_t* __restrict__ wb)
{
    const int idx  = blockIdx.x * 256 + threadIdx.x;   // 24576 slots
    const int lane = idx & 63;
    int t = idx >> 6;
    const int nt   = t % 24;  t /= 24;
    const int comp = t & 1;   t >>= 1;
    const int gemm = t & 1;
    const int ks   = t >> 1;
    const float* src = gemm ? U : K;
    const int n  = nt * 16 + (lane & 15);
    const int kb = ks * 32 + (lane >> 4) * 8;
#pragma unroll
    for (int j = 0; j < 8; j++) {
        const float w = src[(size_t)(kb + j) * 384 + n];
        const ushort_t hi = f2bf(w);
        wb[(size_t)idx * 8 + j] = comp ? f2bf(w - bf2f(hi)) : hi;
    }
}

// ===========================================================================
// GY kernel, R27: G-ONLY (Y2b moved into aggru, which already stages the
// same h rows -- kills the 102MB/step Y2b HBM round-trip). Each wave covers
// ntg = w*2+ntl in 0..7; 48 MFMA/wave; wt table (hi/lo) only. MFMA order
// per accumulator identical to R25 -> bit-identical G.
// ===========================================================================
#define AS1(p) ((const __attribute__((address_space(1))) unsigned int*)(p))
#define AS3(p) ((__attribute__((address_space(3))) unsigned int*)(p))

__global__ __launch_bounds__(256, 4)
void gy_kernel(const ushort_t* __restrict__ hbh, const ushort_t* __restrict__ hbl,
               const ushort_t* __restrict__ wt,
               __half* __restrict__ Gh)
{
    __shared__ __align__(16) ushort_t sact[2][4096];   // hh, hl (8KB each)

    const int tid  = threadIdx.x;
    const int lane = tid & 63;
    const int w    = tid >> 6;
    const int e0   = blockIdx.x * 32;
    const int m16  = lane & 15;
    const int quad = lane >> 4;

    // stage acts in fragment order: granule g = gk*128 + gq*32 + gr*16 + gm
#pragma unroll
    for (int i = 0; i < 2; i++) {
        const int g  = tid + i * 256;
        const int gm = g & 15;
        const int gr = (g >> 4) & 1;
        const int gq = (g >> 5) & 3;
        const int gk = g >> 7;
        const size_t soff = (size_t)(e0 + gr * 16 + gm) * DIM + gk * 32 + gq * 8;
        __builtin_amdgcn_global_load_lds(AS1(hbh + soff), AS3((char*)sact[0] + g * 16), 16, 0, 0);
        __builtin_amdgcn_global_load_lds(AS1(hbl + soff), AS3((char*)sact[1] + g * 16), 16, 0, 0);
    }
    __syncthreads();   // single prologue drain

#define ACT(a_, ks_, rt_) \
    (*(const bf16x8*)((const char*)sact[a_] + (size_t)((ks_) * 2048 + quad * 512 + (rt_) * 256 + m16 * 16)))

    f32x4 acc[2][2] = {};
#pragma unroll
    for (int ks = 0; ks < 4; ks++) {
        bf16x8 ah[2], al[2];
#pragma unroll
        for (int rt = 0; rt < 2; rt++) {
            ah[rt] = ACT(0, ks, rt);
            al[rt] = ACT(1, ks, rt);
        }
#pragma unroll
        for (int ntl = 0; ntl < 2; ntl++) {
            const int nt = w * 2 + ntl;                     // 0..7 (G cols)
            const bf16x8 bh = *(const bf16x8*)(wt + (size_t)((ks * 1024 + nt * 64 + lane) * 8));
            const bf16x8 bl = *(const bf16x8*)(wt + (size_t)((ks * 1024 + 512 + nt * 64 + lane) * 8));
#pragma unroll
            for (int rt = 0; rt < 2; rt++) {
                acc[rt][ntl] = __builtin_amdgcn_mfma_f32_16x16x32_bf16(ah[rt], bh, acc[rt][ntl], 0, 0, 0);
                acc[rt][ntl] = __builtin_amdgcn_mfma_f32_16x16x32_bf16(al[rt], bh, acc[rt][ntl], 0, 0, 0);
                acc[rt][ntl] = __builtin_amdgcn_mfma_f32_16x16x32_bf16(ah[rt], bl, acc[rt][ntl], 0, 0, 0);
            }
        }
    }
#undef ACT
    // C layout: col = lane&15, row = quad*4 + reg
#pragma unroll
    for (int ntl = 0; ntl < 2; ntl++) {
        const int c = (w * 2 + ntl) * 16 + m16;             // 0..127
#pragma unroll
        for (int rt = 0; rt < 2; rt++) {
#pragma unroll
            for (int reg = 0; reg < 4; reg++) {
                const size_t row = (size_t)(e0 + rt * 16 + quad * 4 + reg);
                Gh[row * DIM + c] = __float2half_rn(acc[rt][ntl][reg]);
            }
        }
    }
}

// ===========================================================================
// Fused AGG+GRU kernel, R27: adds in-kernel Y2b phase (bit-identical to
// gy's former Y2b half: same wy fragments, same MFMA order, same bias add).
// Phases: DMA -> bar -> Y2b MFMA -> ylds -> bar -> y-hoist -> bar -> agg
// (x into sact[0..1], reusing the dead ylds space) -> bar -> GRU+epilogue.
// LDS stays 32KB (occupancy unchanged).
// ===========================================================================
__device__ __forceinline__ void aggru_one_dest(
    const __half2* __restrict__ Gh2, const int* __restrict__ sfirst,
    ushort_t* __restrict__ sxh, ushort_t* __restrict__ sxl,
    int rrel, int start, int end, float2 y, int c2, int lane)
{
    float a0 = 0.f, a1 = 0.f;
    int p = start;
    for (; p + 8 <= end; p += 8) {
        int f[8];
#pragma unroll
        for (int j = 0; j < 8; j++) f[j] = sfirst[p + j];
        __half2 g[8];
#pragma unroll
        for (int j = 0; j < 8; j++)
            g[j] = Gh2[(size_t)f[j] * 64 + lane];
#pragma unroll
        for (int j = 0; j < 8; j++) {
            const float2 gf = __half22float2(g[j]);
            a0 += selu_fast(gf.x + y.x);
            a1 += selu_fast(gf.y + y.y);
        }
    }
    if (p + 4 <= end) {
        int f[4];
#pragma unroll
        for (int j = 0; j < 4; j++) f[j] = sfirst[p + j];
        __half2 g[4];
#pragma unroll
        for (int j = 0; j < 4; j++)
            g[j] = Gh2[(size_t)f[j] * 64 + lane];
#pragma unroll
        for (int j = 0; j < 4; j++) {
            const float2 gf = __half22float2(g[j]);
            a0 += selu_fast(gf.x + y.x);
            a1 += selu_fast(gf.y + y.y);
        }
        p += 4;
    }
    for (; p < end; p++) {
        const int f = sfirst[p];
        const float2 gf = __half22float2(Gh2[(size_t)f * 64 + lane]);
        a0 += selu_fast(gf.x + y.x);
        a1 += selu_fast(gf.y + y.y);
    }
    // hi/lo split -> LDS fragment position (ushort idx base, elem even)
    const int ks = c2 >> 5;
    const int qd = (c2 >> 3) & 3;
    const int el = c2 & 7;
    const int base = (ks * 128 + qd * 32 + (rrel >> 4) * 16 + (rrel & 15)) * 8 + el;
    const ushort_t h0 = f2bf(a0);
    const ushort_t h1 = f2bf(a1);
    ushort2 hv, lv;
    hv.x = h0;  hv.y = h1;
    lv.x = f2bf(a0 - bf2f(h0));
    lv.y = f2bf(a1 - bf2f(h1));
    *(ushort2*)(sxh + base) = hv;
    *(ushort2*)(sxl + base) = lv;
}

__global__ __launch_bounds__(512, 4)
void aggru_kernel(const __half2* __restrict__ Gh2,
                  const int* __restrict__ offsets, const int* __restrict__ sfirst,
                  ushort_t* __restrict__ hbh, ushort_t* __restrict__ hbl,
                  const ushort_t* __restrict__ wb, const float* __restrict__ bias,
                  const ushort_t* __restrict__ wy, const float* __restrict__ bmsg)
{
    __shared__ __align__(16) ushort_t sact[4][4096];   // xh, xl, hh, hl (8KB each)

    const int tid  = threadIdx.x;
    const int lane = tid & 63;
    const int w    = tid >> 6;          // 0..7
    const int e0   = blockIdx.x * 32;
    const int m16  = lane & 15;
    const int quad = lane >> 4;

    // ---- phase 0: stage hh/hl in fragment order (granule = tid) ----
    {
        const int gm = tid & 15;
        const int gr = (tid >> 4) & 1;
        const int gq = (tid >> 5) & 3;
        const int gk = tid >> 7;
        const size_t soff = (size_t)(e0 + gr * 16 + gm) * DIM + gk * 32 + gq * 8;
        __builtin_amdgcn_global_load_lds(AS1(hbh + soff), AS3((char*)sact[2] + tid * 16), 16, 0, 0);
        __builtin_amdgcn_global_load_lds(AS1(hbl + soff), AS3((char*)sact[3] + tid * 16), 16, 0, 0);
    }
    __syncthreads();   // drain DMA (Y2b phase needs hh/hl)

#define ACT(a_, ks_, rt_) \
    (*(const bf16x8*)((const char*)sact[a_] + (size_t)((ks_) * 2048 + quad * 512 + (rt_) * 256 + m16 * 16)))

    // ---- phase A: Y2b for this block's 32 rows, col-slice w ----
    {
        f32x4 yacc[2] = {};
#pragma unroll
        for (int ks = 0; ks < 4; ks++) {
            const bf16x8 WyH = *(const bf16x8*)(wy + (size_t)((ks * 1024 + w * 64 + lane) * 8));
            const bf16x8 WyL = *(const bf16x8*)(wy + (size_t)((ks * 1024 + 512 + w * 64 + lane) * 8));
#pragma unroll
            for (int rt = 0; rt < 2; rt++) {
                const bf16x8 hh = ACT(2, ks, rt);
                const bf16x8 hl = ACT(3, ks, rt);
                yacc[rt] = __builtin_amdgcn_mfma_f32_16x16x32_bf16(hh, WyH, yacc[rt], 0, 0, 0);
                yacc[rt] = __builtin_amdgcn_mfma_f32_16x16x32_bf16(hl, WyH, yacc[rt], 0, 0, 0);
                yacc[rt] = __builtin_amdgcn_mfma_f32_16x16x32_bf16(hh, WyL, yacc[rt], 0, 0, 0);
            }
        }
        float* ylds = (float*)sact;                 // 16KB = sact[0..1] (x space, dead)
        const int cc = w * 16 + m16;
        const float bb = bmsg[cc];
#pragma unroll
        for (int rt = 0; rt < 2; rt++) {
#pragma unroll
            for (int reg = 0; reg < 4; reg++) {
                ylds[(rt * 16 + quad * 4 + reg) * 128 + cc] = yacc[rt][reg] + bb;
            }
        }
    }
    __syncthreads();   // y visible to all waves

    // ---- phase B: hoist this wave's 4 dests' y into regs ----
    const int c2 = lane * 2;
    const int r0 = w * 4;
    const float* ylds = (const float*)sact;
    const float2 y0 = *(const float2*)(ylds + (r0 + 0) * 128 + c2);
    const float2 y1 = *(const float2*)(ylds + (r0 + 1) * 128 + c2);
    const float2 y2 = *(const float2*)(ylds + (r0 + 2) * 128 + c2);
    const float2 y3 = *(const float2*)(ylds + (r0 + 3) * 128 + c2);
    __syncthreads();   // ylds dead; sact[0..1] reusable for x

    // ---- phase C: agg for this block's rows; x written into LDS ----
    {
        const int d0 = e0 + w * 4;
        const int o0 = offsets[d0 + 0], o1 = offsets[d0 + 1];
        const int o2 = offsets[d0 + 2], o3 = offsets[d0 + 3], o4 = offsets[d0 + 4];
        aggru_one_dest(Gh2, sfirst, sact[0], sact[1], r0 + 0, o0, o1, y0, c2, lane);
        aggru_one_dest(Gh2, sfirst, sact[0], sact[1], r0 + 1, o1, o2, y1, c2, lane);
        aggru_one_dest(Gh2, sfirst, sact[0], sact[1], r0 + 2, o2, o3, y2, c2, lane);
        aggru_one_dest(Gh2, sfirst, sact[0], sact[1], r0 + 3, o3, o4, y3, c2, lane);
    }
    __syncthreads();   // x LDS-visible

    // ---- phase D: GRU MFMA + epilogue (R25 verbatim) ----
    f32x4 az[2] = {}, ar[2] = {}, ahx[2] = {}, ahh[2] = {};

#define WB(ks_, gm_, cp_, nt_) \
    (*(const bf16x8*)(wb + ((size_t)(((ks_) * 96) + (gm_) * 48 + (cp_) * 24 + (nt_)) * 64 + lane) * 8))

#pragma unroll
    for (int ks = 0; ks < 4; ks++) {
        const bf16x8 KzH = WB(ks, 0, 0, w),      KzL = WB(ks, 0, 1, w);
        const bf16x8 UzH = WB(ks, 1, 0, w),      UzL = WB(ks, 1, 1, w);
        const bf16x8 KrH = WB(ks, 0, 0, w + 8),  KrL = WB(ks, 0, 1, w + 8);
        const bf16x8 UrH = WB(ks, 1, 0, w + 8),  UrL = WB(ks, 1, 1, w + 8);
        const bf16x8 KhH = WB(ks, 0, 0, w + 16), KhL = WB(ks, 0, 1, w + 16);
        const bf16x8 UhH = WB(ks, 1, 0, w + 16), UhL = WB(ks, 1, 1, w + 16);
#pragma unroll
        for (int rt = 0; rt < 2; rt++) {
            const bf16x8 xh = ACT(0, ks, rt);
            const bf16x8 xl = ACT(1, ks, rt);
            const bf16x8 hh = ACT(2, ks, rt);
            const bf16x8 hl = ACT(3, ks, rt);

            az[rt] = __builtin_amdgcn_mfma_f32_16x16x32_bf16(xh, KzH, az[rt], 0, 0, 0);
            az[rt] = __builtin_amdgcn_mfma_f32_16x16x32_bf16(xl, KzH, az[rt], 0, 0, 0);
            az[rt] = __builtin_amdgcn_mfma_f32_16x16x32_bf16(xh, KzL, az[rt], 0, 0, 0);
            az[rt] = __builtin_amdgcn_mfma_f32_16x16x32_bf16(hh, UzH, az[rt], 0, 0, 0);
            az[rt] = __builtin_amdgcn_mfma_f32_16x16x32_bf16(hl, UzH, az[rt], 0, 0, 0);
            az[rt] = __builtin_amdgcn_mfma_f32_16x16x32_bf16(hh, UzL, az[rt], 0, 0, 0);

            ar[rt] = __builtin_amdgcn_mfma_f32_16x16x32_bf16(xh, KrH, ar[rt], 0, 0, 0);
            ar[rt] = __builtin_amdgcn_mfma_f32_16x16x32_bf16(xl, KrH, ar[rt], 0, 0, 0);
            ar[rt] = __builtin_amdgcn_mfma_f32_16x16x32_bf16(xh, KrL, ar[rt], 0, 0, 0);
            ar[rt] = __builtin_amdgcn_mfma_f32_16x16x32_bf16(hh, UrH, ar[rt], 0, 0, 0);
            ar[rt] = __builtin_amdgcn_mfma_f32_16x16x32_bf16(hl, UrH, ar[rt], 0, 0, 0);
            ar[rt] = __builtin_amdgcn_mfma_f32_16x16x32_bf16(hh, UrL, ar[rt], 0, 0, 0);

            ahx[rt] = __builtin_amdgcn_mfma_f32_16x16x32_bf16(xh, KhH, ahx[rt], 0, 0, 0);
            ahx[rt] = __builtin_amdgcn_mfma_f32_16x16x32_bf16(xl, KhH, ahx[rt], 0, 0, 0);
            ahx[rt] = __builtin_amdgcn_mfma_f32_16x16x32_bf16(xh, KhL, ahx[rt], 0, 0, 0);
            ahh[rt] = __builtin_amdgcn_mfma_f32_16x16x32_bf16(hh, UhH, ahh[rt], 0, 0, 0);
            ahh[rt] = __builtin_amdgcn_mfma_f32_16x16x32_bf16(hl, UhH, ahh[rt], 0, 0, 0);
            ahh[rt] = __builtin_amdgcn_mfma_f32_16x16x32_bf16(hh, UhL, ahh[rt], 0, 0, 0);
        }
    }
#undef WB
#undef ACT

    const int c = w * 16 + m16;
    const float l2e  = 1.4426950408889634f;
    const float bzn  = -(bias[c] + bias[384 + c]) * l2e;          // pre-scaled
    const float brn  = -(bias[128 + c] + bias[512 + c]) * l2e;
    const float bxh  = bias[256 + c];
    const float brh  = bias[640 + c];
    const float bxh2 = bxh * (2.f * l2e);

    // h_prev from the staged LDS copy (pre-update bits, exact):
    const int ksc   = w >> 1;
    const int quadc = (2 * w + (m16 >> 3)) & 3;
    const int elem  = m16 & 7;

#pragma unroll
    for (int rt = 0; rt < 2; rt++) {
#pragma unroll
        for (int reg = 0; reg < 4; reg++) {
            const int rrel = rt * 16 + quad * 4 + reg;
            const int row  = e0 + rrel;
            const int lidx = (ksc * 128 + quadc * 32 + rt * 16 + (quad * 4 + reg)) * 8 + elem;
            // sigmoid via exp2+rcp (bias pre-folded with -log2e)
            const float z = __builtin_amdgcn_rcpf(
                1.f + __builtin_amdgcn_exp2f(fmaf(az[rt][reg], -l2e, bzn)));
            const float r = __builtin_amdgcn_rcpf(
                1.f + __builtin_amdgcn_exp2f(fmaf(ar[rt][reg], -l2e, brn)));
            // tanh(s) = 1 - 2/(exp2(2*l2e*s)+1); s = ahx+bxh + r*(ahh+brh)
            const float u   = fmaf(r, ahh[rt][reg] + brh, ahx[rt][reg]);
            const float eh  = __builtin_amdgcn_exp2f(fmaf(u, 2.f * l2e, bxh2));
            const float hc  = fmaf(-2.f, __builtin_amdgcn_rcpf(eh + 1.f), 1.f);
            const float hp = bf2f(sact[2][lidx]) + bf2f(sact[3][lidx]);
            const float hn = fmaf(z, hp - hc, hc);
            const size_t g = (size_t)row * DIM + c;
            const ushort_t hi = f2bf(hn);
            hbh[g] = hi;
            hbl[g] = f2bf(hn - bf2f(hi));
        }
    }
}

#undef AS1
#undef AS3

// ===========================================================================
// Graph pooling + readout
// ===========================================================================
__global__ __launch_bounds__(256)
void pool_kernel(const ushort_t* __restrict__ hbh, const ushort_t* __restrict__ hbl,
                 const int* __restrict__ gid, float* __restrict__ pooled)
{
    const int idx = blockIdx.x * 256 + threadIdx.x;
    const int e = idx >> 7;
    const int n = idx & 127;
    const float hv = bf2f(hbh[idx]) + bf2f(hbl[idx]);
    atomicAdd(pooled + (size_t)gid[e] * DIM + n, hv);
}

__global__ __launch_bounds__(256)
void readout_kernel(const float* __restrict__ pooled,
                    const float* __restrict__ W1, const float* __restrict__ b1,
                    const float* __restrict__ W2, const float* __restrict__ b2,
                    const float* __restrict__ W3, const float* __restrict__ b3,
                    float* __restrict__ out)
{
    __shared__ float sp[DIM];
    __shared__ float s1[R_UNITS];
    __shared__ float s2[R_UNITS];
    const int g = blockIdx.x, tid = threadIdx.x;

    if (tid < DIM) sp[tid] = pooled[(size_t)g * DIM + tid];
    __syncthreads();

    float acc = b1[tid];
    for (int k = 0; k < DIM; k++) acc += sp[k] * W1[(size_t)k * R_UNITS + tid];
    s1[tid] = selu_f(acc);
    __syncthreads();

    acc = b2[tid];
    for (int k = 0; k < R_UNITS; k++) acc += s1[k] * W2[(size_t)k * R_UNITS + tid];
    s2[tid] = selu_f(acc) * W3[tid];
    __syncthreads();

    for (int s = 128; s > 0; s >>= 1) {
        if (tid < s) s2[tid] += s2[tid + s];
        __syncthreads();
    }
    if (tid == 0) out[g] = s2[0] + b3[0];
}

// ===========================================================================
extern "C" void kernel_launch(void* const* d_in, const int* in_sizes, int n_in,
                              void* d_out, int out_size, void* d_ws, size_t ws_size,
                              hipStream_t stream)
{
    const float* link_state = (const float*)d_in[0];
    const int*   gids       = (const int*)d_in[1];
    const int*   first      = (const int*)d_in[2];
    const int*   second     = (const int*)d_in[3];
    const float* Wmsg       = (const float*)d_in[5];
    const float* bmsg       = (const float*)d_in[6];
    const float* gK         = (const float*)d_in[7];
    const float* gU         = (const float*)d_in[8];
    const float* gbias      = (const float*)d_in[9];
    const float* W1         = (const float*)d_in[10];
    const float* b1         = (const float*)d_in[11];
    const float* W2         = (const float*)d_in[12];
    const float* b2         = (const float*)d_in[13];
    const float* W3         = (const float*)d_in[14];
    const float* b3         = (const float*)d_in[15];
    float* out = (float*)d_out;

    // ws layout (16B-aligned segments), R25 layout:
    //   offsets[100004] counts[1e5] cursor[1e5] bsum[128] sfirst[P] ssecond[P]
    //   wt[32768 us] wy[32768 us] wb[196608 us]
    //   hb_hi[E*128 us] hb_lo[E*128 us] (slack: former agg buffers)
    //   Gregion[E*128 f32] (fp16 G uses first half; Y2b slot now unused)
    int* offsets = (int*)d_ws;
    int* counts  = offsets + 100004;
    int* cursor  = counts + E_NUM;
    int* bsum    = cursor + E_NUM;
    int* sfirst  = bsum + 128;
    int* ssecond = sfirst + P_NUM;
    ushort_t* wt     = (ushort_t*)(ssecond + P_NUM);
    ushort_t* wy     = wt + 32768;
    ushort_t* wb     = wy + 32768;
    ushort_t* hb_hi  = wb + 196608;
    ushort_t* hb_lo  = hb_hi + (size_t)E_NUM * DIM;
    ushort_t* slack  = hb_lo + (size_t)E_NUM * DIM;
    float*    Gf     = (float*)(slack + 2 * (size_t)E_NUM * DIM);
    __half*   Gh     = (__half*)Gf;                   // fp16 alias

    // ---- one-time prep ----
    hipMemsetAsync(counts, 0, E_NUM * sizeof(int), stream);
    hipMemsetAsync(cursor, 0, E_NUM * sizeof(int), stream);
    hist_kernel<<<P_NUM / 256, 256, 0, stream>>>(second, counts);
    scanA_kernel<<<98, 1024, 0, stream>>>(counts, offsets, bsum);
    scanB_kernel<<<1, 1, 0, stream>>>(bsum, offsets);
    scanC_kernel<<<98, 1024, 0, stream>>>(offsets, bsum);
    fill_kernel<<<P_NUM / 256, 256, 0, stream>>>(first, second, offsets, cursor,
                                                 sfirst, ssecond);
    wsplit_build_kernel<<<32, 256, 0, stream>>>(Wmsg, wt, wy);
    wb_build_kernel<<<96, 256, 0, stream>>>(gK, gU, wb);
    cast_h_kernel<<<(E_NUM * DIM) / 256, 256, 0, stream>>>(link_state, hb_hi, hb_lo);

    // ---- message-passing steps ----
    for (int t = 0; t < T_STEPS; t++) {
        gy_kernel<<<E_NUM / 32, 256, 0, stream>>>(hb_hi, hb_lo, wt, Gh);
        aggru_kernel<<<E_NUM / 32, 512, 0, stream>>>((const __half2*)Gh,
                                                     offsets, sfirst,
                                                     hb_hi, hb_lo,
                                                     wb, gbias, wy, bmsg);
    }

    // ---- pool + readout (G region reused as pooled buffer) ----
    float* pooled = Gf;
    hipMemsetAsync(pooled, 0, (size_t)G_NUM * DIM * sizeof(float), stream);
    pool_kernel<<<(E_NUM * DIM) / 256, 256, 0, stream>>>(hb_hi, hb_lo, gids, pooled);
    readout_kernel<<<G_NUM, 256, 0, stream>>>(pooled, W1, b1, W2, b2, W3, b3, out);
}